// Round 3
// baseline (325.878 us; speedup 1.0000x reference)
//
#include <hip/hip_runtime.h>
#include <hip/hip_bf16.h>

typedef __bf16 bf16_t;
typedef bf16_t bf16x4 __attribute__((ext_vector_type(4)));
typedef bf16_t bf16x8 __attribute__((ext_vector_type(8)));
typedef float f32x4 __attribute__((ext_vector_type(4)));

#define MFMA16(a, b, c) __builtin_amdgcn_mfma_f32_16x16x32_bf16((a), (b), (c), 0, 0, 0)

// ---------------------------------------------------------------------------
// prep kernels (run each launch; deterministic)
// ---------------------------------------------------------------------------
__global__ void transpose_to_bf16(const float* __restrict__ in, bf16_t* __restrict__ outp,
                                  int K, int N) {
  // outp[n][k] = (bf16) in[k][n];  in is K x N row-major
  __shared__ float tile[32][33];
  const int k0 = blockIdx.x * 32;
  const int n0 = blockIdx.y * 32;
  const int tx = threadIdx.x;  // 0..31
  const int ty = threadIdx.y;  // 0..7
#pragma unroll
  for (int i = 0; i < 32; i += 8)
    tile[ty + i][tx] = in[(size_t)(k0 + ty + i) * N + (n0 + tx)];
  __syncthreads();
#pragma unroll
  for (int i = 0; i < 32; i += 8)
    outp[(size_t)(n0 + ty + i) * K + (k0 + tx)] = (bf16_t)tile[tx][ty + i];
}

__global__ void rope_table(const float* __restrict__ invf, float* __restrict__ ct,
                           float* __restrict__ st) {
  const int idx = blockIdx.x * 256 + threadIdx.x;  // 0..2047 = 64*32
  const int t = idx >> 5;
  const int i = idx & 31;
  const float f = (float)t * invf[i];
  ct[idx] = cosf(f);
  st[idx] = sinf(f);
}

// ---------------------------------------------------------------------------
// fused temporal-axial attention
// grid: 2048 blocks = (b, hh*32+ww); block: 256 threads (4 waves, wave w = head w)
// ---------------------------------------------------------------------------
__global__ __launch_bounds__(256, 1) void taa_fused(
    const float* __restrict__ x, const bf16_t* __restrict__ wqkvT,
    const bf16_t* __restrict__ woutT, const float* __restrict__ bout,
    const float* __restrict__ ropec, const float* __restrict__ ropes,
    float* __restrict__ out) {
  // LDS regions (all rows padded 64 -> 72 elems = 144B stride: banks spread 8-way)
  __shared__ __attribute__((aligned(16))) bf16_t sQ[4][64][72];   // [h][t][d]; later o_all[64][264]
  __shared__ __attribute__((aligned(16))) bf16_t sK[4][64][72];   // [h][s][d]
  __shared__ __attribute__((aligned(16))) bf16_t sV[4][64][72];   // [h][d][t]  (transposed)
  __shared__ __attribute__((aligned(16))) bf16_t sR1[4][64][72];  // x-tile[64][264] / probs[h][64][72]

  const int tid = threadIdx.x;
  const int w = tid >> 6;   // wave == head
  const int l = tid & 63;   // lane
  const int l16 = l & 15;
  const int g = l >> 4;     // 0..3

  const int wg = blockIdx.x;
  const int b = wg >> 10;
  const int sp = wg & 1023;  // hh*32+ww

  const int TS = 1024 * 256;  // token (time) stride in elements
  const float* xp = x + (size_t)((b * 64) * 1024 + sp) * 256;
  float* op = out + (size_t)((b * 64) * 1024 + sp) * 256;

  // ---- phase 1: x tile (64 x 256 f32) -> LDS bf16 ----
  {
    bf16_t(*xt)[264] = (bf16_t(*)[264]) & sR1[0][0][0];
#pragma unroll
    for (int it = 0; it < 16; ++it) {
      const int idx = tid + it * 256;  // 0..4095
      const int t = idx >> 6;
      const int c4 = (idx & 63) * 4;
      const float4 v = *(const float4*)(xp + (size_t)t * TS + c4);
      bf16x4 o = {(bf16_t)v.x, (bf16_t)v.y, (bf16_t)v.z, (bf16_t)v.w};
      *(bf16x4*)&xt[t][c4] = o;
    }
  }
  __syncthreads();

  // ---- phase 2: QKV projection + RoPE; wave w computes head w's q/k/v ----
  {
    const bf16_t(*xt)[264] = (const bf16_t(*)[264]) & sR1[0][0][0];
    for (int c = 0; c < 3; ++c) {  // 0:q 1:k 2:v
      const int colbase = c * 256 + w * 64;
      f32x4 acc[4][4] = {};
#pragma unroll
      for (int k0 = 0; k0 < 256; k0 += 32) {
        const int ko = k0 + 8 * g;
        bf16x8 af[4], bf[4];
#pragma unroll
        for (int m = 0; m < 4; ++m) af[m] = *(const bf16x8*)&xt[m * 16 + l16][ko];
#pragma unroll
        for (int n = 0; n < 4; ++n)
          bf[n] = *(const bf16x8*)&wqkvT[(size_t)(colbase + n * 16 + l16) * 256 + ko];
#pragma unroll
        for (int m = 0; m < 4; ++m)
#pragma unroll
          for (int n = 0; n < 4; ++n) acc[m][n] = MFMA16(af[m], bf[n], acc[m][n]);
      }
      if (c < 2) {
        bf16_t(*dst)[72] = (c == 0) ? sQ[w] : sK[w];
        // fold softmax scale (1/8) and log2(e) into q so scores are exp2-domain
        const float qs = (c == 0) ? (0.125f * 1.44269504088896f) : 1.0f;
#pragma unroll
        for (int m = 0; m < 4; ++m)
#pragma unroll
          for (int n = 0; n < 4; ++n)
#pragma unroll
            for (int r = 0; r < 4; ++r) {
              const float v = acc[m][n][r];
              const float p = __shfl_xor(v, 1);  // partner column (col^1)
              const int t = m * 16 + 4 * g + r;
              const int dl = n * 16 + l16;  // dim within head
              const int fi = t * 32 + (dl >> 1);
              const float cv = ropec[fi], sv = ropes[fi];
              const float o = (dl & 1) ? (v * cv + p * sv) : (v * cv - p * sv);
              dst[t][dl] = (bf16_t)(o * qs);
            }
      } else {
#pragma unroll
        for (int m = 0; m < 4; ++m)
#pragma unroll
          for (int n = 0; n < 4; ++n)
#pragma unroll
            for (int r = 0; r < 4; ++r) {
              const int t = m * 16 + 4 * g + r;
              const int dl = n * 16 + l16;
              sV[w][dl][t] = (bf16_t)acc[m][n][r];  // store transposed [d][t]
            }
      }
    }
  }
  __syncthreads();

  // ---- phase 3: causal attention for head w (one wave, 64x64) ----
  f32x4 oacc[4][4] = {};
  {
    f32x4 sc[4][4] = {};
#pragma unroll
    for (int ks = 0; ks < 2; ++ks) {
      const int ko = ks * 32 + 8 * g;
      bf16x8 af[4], bf[4];
#pragma unroll
      for (int m = 0; m < 4; ++m) af[m] = *(const bf16x8*)&sQ[w][m * 16 + l16][ko];
#pragma unroll
      for (int n = 0; n < 4; ++n) bf[n] = *(const bf16x8*)&sK[w][n * 16 + l16][ko];
#pragma unroll
      for (int m = 0; m < 4; ++m)
#pragma unroll
        for (int n = 0; n < 4; ++n) sc[m][n] = MFMA16(af[m], bf[n], sc[m][n]);
    }
    // softmax (exp2 domain; scores already scaled by 0.125*log2e via q)
    bf16_t(*probs)[72] = sR1[w];
#pragma unroll
    for (int m = 0; m < 4; ++m)
#pragma unroll
      for (int r = 0; r < 4; ++r) {
        const int row = m * 16 + 4 * g + r;
        float vals[4];
        float mx = -3.0e38f;
#pragma unroll
        for (int n = 0; n < 4; ++n) {
          const int col = n * 16 + l16;
          vals[n] = (col <= row) ? sc[m][n][r] : -3.0e38f;
          mx = fmaxf(mx, vals[n]);
        }
#pragma unroll
        for (int s = 1; s < 16; s <<= 1) mx = fmaxf(mx, __shfl_xor(mx, s));
        float p[4], sum = 0.f;
#pragma unroll
        for (int n = 0; n < 4; ++n) {
          p[n] = exp2f(vals[n] - mx);
          sum += p[n];
        }
#pragma unroll
        for (int s = 1; s < 16; s <<= 1) sum += __shfl_xor(sum, s);
        const float inv = 1.0f / sum;
#pragma unroll
        for (int n = 0; n < 4; ++n) probs[row][n * 16 + l16] = (bf16_t)(p[n] * inv);
      }
    // PV: o = probs @ v   (A = probs row-major, B = v via transposed sV)
#pragma unroll
    for (int ks = 0; ks < 2; ++ks) {
      const int ko = ks * 32 + 8 * g;
      bf16x8 af[4], bf[4];
#pragma unroll
      for (int m = 0; m < 4; ++m) af[m] = *(const bf16x8*)&probs[m * 16 + l16][ko];
#pragma unroll
      for (int n = 0; n < 4; ++n) bf[n] = *(const bf16x8*)&sV[w][n * 16 + l16][ko];
#pragma unroll
      for (int m = 0; m < 4; ++m)
#pragma unroll
        for (int n = 0; n < 4; ++n) oacc[m][n] = MFMA16(af[m], bf[n], oacc[m][n]);
    }
  }
  __syncthreads();  // all waves done reading q/k before overwrite

  // ---- phase 4: o -> LDS (overlay on sQ region), cols = head*64 + d ----
  {
    bf16_t(*oall)[264] = (bf16_t(*)[264]) & sQ[0][0][0];
#pragma unroll
    for (int m = 0; m < 4; ++m)
#pragma unroll
      for (int n = 0; n < 4; ++n)
#pragma unroll
        for (int r = 0; r < 4; ++r) {
          const int t = m * 16 + 4 * g + r;
          const int col = w * 64 + n * 16 + l16;
          oall[t][col] = (bf16_t)oacc[m][n][r];
        }
  }
  __syncthreads();

  // ---- phase 5: output projection (wave w -> out cols w*64..w*64+63) ----
  {
    const bf16_t(*oall)[264] = (const bf16_t(*)[264]) & sQ[0][0][0];
    f32x4 acc[4][4] = {};
#pragma unroll
    for (int k0 = 0; k0 < 256; k0 += 32) {
      const int ko = k0 + 8 * g;
      bf16x8 af[4], bf[4];
#pragma unroll
      for (int m = 0; m < 4; ++m) af[m] = *(const bf16x8*)&oall[m * 16 + l16][ko];
#pragma unroll
      for (int n = 0; n < 4; ++n)
        bf[n] = *(const bf16x8*)&woutT[(size_t)(w * 64 + n * 16 + l16) * 256 + ko];
#pragma unroll
      for (int m = 0; m < 4; ++m)
#pragma unroll
        for (int n = 0; n < 4; ++n) acc[m][n] = MFMA16(af[m], bf[n], acc[m][n]);
    }
    float bb[4];
#pragma unroll
    for (int n = 0; n < 4; ++n) bb[n] = bout[w * 64 + n * 16 + l16];
#pragma unroll
    for (int m = 0; m < 4; ++m)
#pragma unroll
      for (int n = 0; n < 4; ++n)
#pragma unroll
        for (int r = 0; r < 4; ++r) {
          const int t = m * 16 + 4 * g + r;
          const int col = w * 64 + n * 16 + l16;
          op[(size_t)t * TS + col] = acc[m][n][r] + bb[n];
        }
  }
}

// ---------------------------------------------------------------------------
extern "C" void kernel_launch(void* const* d_in, const int* in_sizes, int n_in,
                              void* d_out, int out_size, void* d_ws, size_t ws_size,
                              hipStream_t stream) {
  const float* x = (const float*)d_in[0];
  const float* wqkv = (const float*)d_in[1];
  const float* wout = (const float*)d_in[2];
  const float* bout = (const float*)d_in[3];
  const float* invf = (const float*)d_in[4];
  float* out = (float*)d_out;

  char* ws = (char*)d_ws;
  bf16_t* wqkvT = (bf16_t*)ws;                         // 768*256*2 = 393216 B
  bf16_t* woutT = (bf16_t*)(ws + 393216);              // 256*256*2 = 131072 B
  float* ropec = (float*)(ws + 393216 + 131072);       // 64*32*4  = 8192 B
  float* ropes = (float*)(ws + 393216 + 131072 + 8192);

  transpose_to_bf16<<<dim3(8, 24), dim3(32, 8), 0, stream>>>(wqkv, wqkvT, 256, 768);
  transpose_to_bf16<<<dim3(8, 8), dim3(32, 8), 0, stream>>>(wout, woutT, 256, 256);
  rope_table<<<8, 256, 0, stream>>>(invf, ropec, ropes);

  taa_fused<<<2048, 256, 0, stream>>>(x, wqkvT, woutT, bout, ropec, ropes, out);
}

// Round 4
// 246.453 us; speedup vs baseline: 1.3223x; 1.3223x over previous
//
#include <hip/hip_runtime.h>
#include <hip/hip_bf16.h>

typedef __bf16 bf16_t;
typedef bf16_t bf16x4 __attribute__((ext_vector_type(4)));
typedef bf16_t bf16x8 __attribute__((ext_vector_type(8)));
typedef float f32x4 __attribute__((ext_vector_type(4)));

#define MFMA16(a, b, c) __builtin_amdgcn_mfma_f32_16x16x32_bf16((a), (b), (c), 0, 0, 0)

// element-index XOR swizzle (bf16 elems): == byte-XOR of bits 4..6 keyed by row&7
__device__ __forceinline__ int sxi(int row, int e) { return row * 256 + (e ^ ((row & 7) << 3)); }  // 256-col tile
__device__ __forceinline__ int ski(int row, int e) { return row * 64 + (e ^ ((row & 7) << 3)); }   // 64-col tile

// ---------------------------------------------------------------------------
// prep kernels (run each launch; deterministic)
// ---------------------------------------------------------------------------
__global__ void transpose_to_bf16(const float* __restrict__ in, bf16_t* __restrict__ outp,
                                  int K, int N) {
  __shared__ float tile[32][33];
  const int k0 = blockIdx.x * 32;
  const int n0 = blockIdx.y * 32;
  const int tx = threadIdx.x;
  const int ty = threadIdx.y;
#pragma unroll
  for (int i = 0; i < 32; i += 8)
    tile[ty + i][tx] = in[(size_t)(k0 + ty + i) * N + (n0 + tx)];
  __syncthreads();
#pragma unroll
  for (int i = 0; i < 32; i += 8)
    outp[(size_t)(n0 + ty + i) * K + (k0 + tx)] = (bf16_t)tile[tx][ty + i];
}

__global__ void rope_table(const float* __restrict__ invf, float2* __restrict__ cs) {
  const int idx = blockIdx.x * 256 + threadIdx.x;  // 0..2047 = 64*32
  const int t = idx >> 5;
  const int i = idx & 31;
  const float f = (float)t * invf[i];
  cs[idx] = make_float2(cosf(f), sinf(f));
}

// ---------------------------------------------------------------------------
// fused temporal-axial attention, 64KB LDS, 2 blocks/CU
// grid: 2048 = (b, hh*32+ww); block: 256 threads (4 waves, wave w = head w)
// ---------------------------------------------------------------------------
__global__ __launch_bounds__(256, 2) void taa_fused(
    const float* __restrict__ x, const bf16_t* __restrict__ wqkvT,
    const bf16_t* __restrict__ woutT, const float* __restrict__ bout,
    const float2* __restrict__ ropecs, float* __restrict__ out) {
  // sX: x-tile[64][256] -> (per-wave 8KB Q then P slices) -> O-tile[64][256]
  __shared__ __attribute__((aligned(16))) bf16_t sX[64 * 256];  // 32 KB
  __shared__ __attribute__((aligned(16))) bf16_t sK[4][64 * 64];  // 32 KB, K[s][dd] per head

  const int tid = threadIdx.x;
  const int w = tid >> 6;   // wave == head
  const int l = tid & 63;
  const int l16 = l & 15;
  const int g = l >> 4;  // 0..3

  const int wg = blockIdx.x;
  const int b = wg >> 10;
  const int sp = wg & 1023;

  const size_t TS = 1024 * 256;  // time stride in elements
  const float* xp = x + (size_t)((b * 64) * 1024 + sp) * 256;
  float* op = out + (size_t)((b * 64) * 1024 + sp) * 256;

  // ---- phase 1: x tile (64x256 f32) -> sX bf16 (swizzled) ----
#pragma unroll
  for (int it = 0; it < 16; ++it) {
    const int idx = tid + it * 256;
    const int t = idx >> 6;
    const int c = (idx & 63) * 4;
    const float4 v = *(const float4*)(xp + (size_t)t * TS + c);
    bf16x4 o4;
    o4[0] = (bf16_t)v.x; o4[1] = (bf16_t)v.y; o4[2] = (bf16_t)v.z; o4[3] = (bf16_t)v.w;
    *(bf16x4*)&sX[sxi(t, c)] = o4;
  }
  __syncthreads();  // B1: x staged

  // ---- phase 2: QKV projection (normal orientation), RoPE in-register ----
  f32x4 qacc[4][4] = {};
  f32x4 vacc[4][4] = {};
  {
    // q
#pragma unroll
    for (int k0 = 0; k0 < 256; k0 += 32) {
      const int ko = k0 + 8 * g;
      bf16x8 af[4], bf[4];
#pragma unroll
      for (int m = 0; m < 4; ++m) af[m] = *(const bf16x8*)&sX[sxi(16 * m + l16, ko)];
#pragma unroll
      for (int n = 0; n < 4; ++n)
        bf[n] = *(const bf16x8*)&wqkvT[(size_t)(w * 64 + 16 * n + l16) * 256 + ko];
#pragma unroll
      for (int m = 0; m < 4; ++m)
#pragma unroll
        for (int n = 0; n < 4; ++n) qacc[m][n] = MFMA16(af[m], bf[n], qacc[m][n]);
    }
    // rope(q) + fold 0.125*log2(e)
    const float qs = 0.125f * 1.44269504088896f;
#pragma unroll
    for (int m = 0; m < 4; ++m)
#pragma unroll
      for (int n = 0; n < 4; ++n)
#pragma unroll
        for (int r = 0; r < 4; ++r) {
          const int t = 16 * m + 4 * g + r, dd = 16 * n + l16;
          const float v = qacc[m][n][r];
          const float p = __shfl_xor(v, 1);
          const float2 cs = ropecs[t * 32 + (dd >> 1)];
          const float o = (dd & 1) ? (v * cs.x + p * cs.y) : (v * cs.x - p * cs.y);
          qacc[m][n][r] = o * qs;
        }
    // k
    f32x4 kacc[4][4] = {};
#pragma unroll
    for (int k0 = 0; k0 < 256; k0 += 32) {
      const int ko = k0 + 8 * g;
      bf16x8 af[4], bf[4];
#pragma unroll
      for (int m = 0; m < 4; ++m) af[m] = *(const bf16x8*)&sX[sxi(16 * m + l16, ko)];
#pragma unroll
      for (int n = 0; n < 4; ++n)
        bf[n] = *(const bf16x8*)&wqkvT[(size_t)(256 + w * 64 + 16 * n + l16) * 256 + ko];
#pragma unroll
      for (int m = 0; m < 4; ++m)
#pragma unroll
        for (int n = 0; n < 4; ++n) kacc[m][n] = MFMA16(af[m], bf[n], kacc[m][n]);
    }
    // rope(k) + store K[s][dd] to wave-private sK[w] (no barrier needed)
#pragma unroll
    for (int m = 0; m < 4; ++m)
#pragma unroll
      for (int n = 0; n < 4; ++n)
#pragma unroll
        for (int r = 0; r < 4; ++r) {
          const int s = 16 * m + 4 * g + r, dd = 16 * n + l16;
          const float v = kacc[m][n][r];
          const float p = __shfl_xor(v, 1);
          const float2 cs = ropecs[s * 32 + (dd >> 1)];
          const float o = (dd & 1) ? (v * cs.x + p * cs.y) : (v * cs.x - p * cs.y);
          sK[w][ski(s, dd)] = (bf16_t)o;
        }
    // v
#pragma unroll
    for (int k0 = 0; k0 < 256; k0 += 32) {
      const int ko = k0 + 8 * g;
      bf16x8 af[4], bf[4];
#pragma unroll
      for (int m = 0; m < 4; ++m) af[m] = *(const bf16x8*)&sX[sxi(16 * m + l16, ko)];
#pragma unroll
      for (int n = 0; n < 4; ++n)
        bf[n] = *(const bf16x8*)&wqkvT[(size_t)(512 + w * 64 + 16 * n + l16) * 256 + ko];
#pragma unroll
      for (int m = 0; m < 4; ++m)
#pragma unroll
        for (int n = 0; n < 4; ++n) vacc[m][n] = MFMA16(af[m], bf[n], vacc[m][n]);
    }
  }
  __syncthreads();  // B2: all waves done reading x -> sX slices reusable

  // ---- store Q[t][dd] into wave-private slice of sX ----
  bf16_t* slice = &sX[w * 4096];
#pragma unroll
  for (int m = 0; m < 4; ++m)
#pragma unroll
    for (int n = 0; n < 4; ++n)
#pragma unroll
      for (int r = 0; r < 4; ++r) {
        const int t = 16 * m + 4 * g + r, dd = 16 * n + l16;
        slice[ski(t, dd)] = (bf16_t)qacc[m][n][r];
      }

  // ---- phase 3a: S^T = K @ Q^T  (A = K from sK, B = Q^T from slice) ----
  f32x4 sc[4][4] = {};  // (s = 16m+4g+r, t = 16n+l16)
#pragma unroll
  for (int ks = 0; ks < 2; ++ks) {
    const int ko = ks * 32 + 8 * g;
    bf16x8 af[4], bf[4];
#pragma unroll
    for (int m = 0; m < 4; ++m) af[m] = *(const bf16x8*)&sK[w][ski(16 * m + l16, ko)];
#pragma unroll
    for (int n = 0; n < 4; ++n) bf[n] = *(const bf16x8*)&slice[ski(16 * n + l16, ko)];
#pragma unroll
    for (int m = 0; m < 4; ++m)
#pragma unroll
      for (int n = 0; n < 4; ++n) sc[m][n] = MFMA16(af[m], bf[n], sc[m][n]);
  }

  // ---- phase 3b: causal softmax over s (per-lane 16 vals + 2 shfl), P -> slice ----
#pragma unroll
  for (int n = 0; n < 4; ++n) {
    const int t = 16 * n + l16;
    float vals[16];
    float mx = -3.0e38f;
#pragma unroll
    for (int m = 0; m < 4; ++m)
#pragma unroll
      for (int r = 0; r < 4; ++r) {
        const int s = 16 * m + 4 * g + r;
        const float v = (s <= t) ? sc[m][n][r] : -3.0e38f;
        vals[4 * m + r] = v;
        mx = fmaxf(mx, v);
      }
    mx = fmaxf(mx, __shfl_xor(mx, 16));
    mx = fmaxf(mx, __shfl_xor(mx, 32));
    float sum = 0.f;
#pragma unroll
    for (int i = 0; i < 16; ++i) {
      vals[i] = exp2f(vals[i] - mx);
      sum += vals[i];
    }
    sum += __shfl_xor(sum, 16);
    sum += __shfl_xor(sum, 32);
    const float inv = 1.0f / sum;
#pragma unroll
    for (int m = 0; m < 4; ++m) {
      bf16x4 p4;
#pragma unroll
      for (int r = 0; r < 4; ++r) p4[r] = (bf16_t)(vals[4 * m + r] * inv);
      *(bf16x4*)&slice[ski(t, 16 * m + 4 * g)] = p4;  // P[t][s..s+3]
    }
  }

  // ---- phase 3c: O = P @ V (A = P from slice; B = V built from vacc via shfl) ----
  f32x4 oacc[4][4] = {};
#pragma unroll
  for (int ks = 0; ks < 2; ++ks) {
    const int ko = ks * 32 + 8 * g;
    bf16x8 af[4];
#pragma unroll
    for (int m = 0; m < 4; ++m) af[m] = *(const bf16x8*)&slice[ski(16 * m + l16, ko)];
    bf16x8 bfv[4];
    const int srcA = (2 * (g & 1)) * 16 + l16;
#pragma unroll
    for (int n = 0; n < 4; ++n) {
      bf16x8 f;
#pragma unroll
      for (int h = 0; h < 2; ++h) {
        const int src = srcA + h * 16;
#pragma unroll
        for (int r = 0; r < 4; ++r) {
          const float v0 = __shfl(vacc[2 * ks][n][r], src);
          const float v1 = __shfl(vacc[2 * ks + 1][n][r], src);
          f[4 * h + r] = (bf16_t)((g & 2) ? v1 : v0);
        }
      }
      bfv[n] = f;
    }
#pragma unroll
    for (int m = 0; m < 4; ++m)
#pragma unroll
      for (int n = 0; n < 4; ++n) oacc[m][n] = MFMA16(af[m], bfv[n], oacc[m][n]);
  }
  __syncthreads();  // B3: all waves done reading their P slices

  // ---- phase 4: O -> sX[t][w*64+d] (whole tile, swizzled) ----
#pragma unroll
  for (int m = 0; m < 4; ++m)
#pragma unroll
    for (int n = 0; n < 4; ++n)
#pragma unroll
      for (int r = 0; r < 4; ++r) {
        const int t = 16 * m + 4 * g + r, col = w * 64 + 16 * n + l16;
        sX[sxi(t, col)] = (bf16_t)oacc[m][n][r];
      }
  __syncthreads();  // B4

  // ---- phase 5: out = O @ w_out + b (wave w -> cols w*64..) ----
  f32x4 acc[4][4] = {};
#pragma unroll
  for (int k0 = 0; k0 < 256; k0 += 32) {
    const int ko = k0 + 8 * g;
    bf16x8 af[4], bf[4];
#pragma unroll
    for (int m = 0; m < 4; ++m) af[m] = *(const bf16x8*)&sX[sxi(16 * m + l16, ko)];
#pragma unroll
    for (int n = 0; n < 4; ++n)
      bf[n] = *(const bf16x8*)&woutT[(size_t)(w * 64 + 16 * n + l16) * 256 + ko];
#pragma unroll
    for (int m = 0; m < 4; ++m)
#pragma unroll
      for (int n = 0; n < 4; ++n) acc[m][n] = MFMA16(af[m], bf[n], acc[m][n]);
  }
  float bb[4];
#pragma unroll
  for (int n = 0; n < 4; ++n) bb[n] = bout[w * 64 + 16 * n + l16];
#pragma unroll
  for (int m = 0; m < 4; ++m)
#pragma unroll
    for (int n = 0; n < 4; ++n)
#pragma unroll
      for (int r = 0; r < 4; ++r) {
        const int t = 16 * m + 4 * g + r, col = w * 64 + 16 * n + l16;
        op[(size_t)t * TS + col] = acc[m][n][r] + bb[n];
      }
}

// ---------------------------------------------------------------------------
extern "C" void kernel_launch(void* const* d_in, const int* in_sizes, int n_in,
                              void* d_out, int out_size, void* d_ws, size_t ws_size,
                              hipStream_t stream) {
  const float* x = (const float*)d_in[0];
  const float* wqkv = (const float*)d_in[1];
  const float* wout = (const float*)d_in[2];
  const float* bout = (const float*)d_in[3];
  const float* invf = (const float*)d_in[4];
  float* out = (float*)d_out;

  char* ws = (char*)d_ws;
  bf16_t* wqkvT = (bf16_t*)ws;                    // 768*256*2 = 393216 B
  bf16_t* woutT = (bf16_t*)(ws + 393216);         // 256*256*2 = 131072 B
  float2* ropecs = (float2*)(ws + 393216 + 131072);  // 2048*8 = 16384 B

  transpose_to_bf16<<<dim3(8, 24), dim3(32, 8), 0, stream>>>(wqkv, wqkvT, 256, 768);
  transpose_to_bf16<<<dim3(8, 8), dim3(32, 8), 0, stream>>>(wout, woutT, 256, 256);
  rope_table<<<8, 256, 0, stream>>>(invf, ropecs);

  taa_fused<<<2048, 256, 0, stream>>>(x, wqkvT, woutT, bout, ropecs, out);
}